// Round 4
// baseline (177.769 us; speedup 1.0000x reference)
//
#include <hip/hip_runtime.h>
#include <hip/hip_fp16.h>

#define BATCH   1024
#define IN      1024
#define OUT     40960
#define KF      7
#define BT      16           // batch rows per block: two 8-row fp16 tables
#define NO      4            // output columns per thread
#define THREADS 256
#define OTILE   (THREADS * NO)   // 1024 outputs per block
#define CHUNKS  (OUT / 64)       // 640 chunks of 64 consecutive outputs

// Workspace layout (repacked once per launch by repack_kernel):
//   pmeta : uint2 [CHUNKS][KF][64]  {x = idx<<4 (LDS byte off), y = f32 val bits}
//                                   lane-major -> one coalesced dwordx2 per (o,k)
//   xpk   : f16   [BATCH/8][IN][8]  x rounded fp16, 8 batch rows per 16-B granule
#define PMETA_BYTES ((size_t)CHUNKS * KF * 64 * 8)        // 2,293,760
#define XPK_BYTES   ((size_t)(BATCH / 8) * IN * 8 * 2)    // 2,097,152

// Round-3 accounting: sparse_proj ~67us vs 27us write floor. Non-floor terms:
// LDS gather (2240 wave-b128/CU, stochastic-conflict cost 17-35us), metadata+
// stage VMEM issue (~16us), end-of-kernel store burst overlapping poorly with
// the LDS phase. This version: (1) BT=16 via two 8-row tables -> metadata and
// staging per work halve (gather statistics unchanged: 16-B granule, i mod 8
// bank groups per table); (2) 8-B packed {off,val} record -> one dwordx2 per
// (o,k); (3) stores interleaved per no-group -> write stream spread across
// kernel, live acc drops to 16 regs -> launch_bounds(256,5), 20 waves/CU.

__global__ __launch_bounds__(THREADS)
void repack_kernel(const float* __restrict__ x, const float* __restrict__ vals,
                   const int* __restrict__ idx,
                   uint2* __restrict__ pmeta, __half* __restrict__ xpk)
{
    const int gid = blockIdx.x * THREADS + threadIdx.x;
    if (blockIdx.x < 512) {
        // ---- part A: x[1024][1024] f32 -> xpk[g][i][8] f16 ----
        const int g = gid >> 10;        // batch group 0..127
        const int i = gid & 1023;       // column
        const float* xb = x + (size_t)g * 8 * IN + i;
        union { __half h[8]; float4 f; } u;
#pragma unroll
        for (int r = 0; r < 8; ++r) u.h[r] = __float2half_rn(xb[(size_t)r * IN]);
        *(float4*)&xpk[(size_t)gid * 8] = u.f;   // coalesced 16-B store
    } else {
        // ---- part B: idx/vals [OUT][KF] -> pmeta[CHUNKS][KF][64] ----
        const int t2 = gid - 512 * THREADS;      // 0 .. 286719
        const int c  = t2 / (KF * 64);
        const int r  = t2 % (KF * 64);
        const int k  = r >> 6;
        const int l  = r & 63;
        const size_t src = (size_t)(c * 64 + l) * KF + k;
        uint2 m;
        m.x = (unsigned)(idx[src] << 4);         // byte offset into xs table
        m.y = __float_as_uint(vals[src]);
        pmeta[t2] = m;
    }
}

__global__ __launch_bounds__(THREADS, 5)
void sparse_proj(const uint2* __restrict__ pmeta, const __half* __restrict__ xpk,
                 float* __restrict__ y)
{
    // two 8-row tables, 16 KB apart: xs[h*8192 + i*16B] = rows b0+8h .. b0+8h+7
    __shared__ __align__(16) __half xs[2 * IN * 8];   // 32 KB -> 5 blocks/CU

    const int t     = threadIdx.x;
    const int b0    = blockIdx.y * BT;
    const int obase = blockIdx.x * OTILE + t;

    // ---- stage: straight 32 KB copy, already fp16 + gather-layout ----
    {
        const float4* src = (const float4*)(xpk + (size_t)blockIdx.y * 2 * IN * 8);
        float4* dst = (float4*)xs;
#pragma unroll
        for (int r = 0; r < 8; ++r) dst[t + r * THREADS] = src[t + r * THREADS];
    }
    __syncthreads();

    const int w    = t >> 6;
    const int lane = t & 63;

#pragma unroll
    for (int no = 0; no < NO; ++no) {
        // chunk c owns outputs [c*64, c*64+64); this thread's o = c*64 + lane
        // = obase + no*256 (matches the store below)
        const int c = blockIdx.x * 16 + no * 4 + w;
        const uint2* mp = pmeta + (size_t)c * (KF * 64) + lane;

        float acc[BT];
#pragma unroll
        for (int r = 0; r < BT; ++r) acc[r] = 0.0f;

#pragma unroll
        for (int k = 0; k < KF; ++k) {
            const uint2 m = mp[k * 64];          // one coalesced dwordx2
            const unsigned off = m.x;            // i*16
            const float v = __uint_as_float(m.y);
            const float4 g0 = *(const float4*)((const char*)xs + off);          // rows 0-7
            const float4 g1 = *(const float4*)((const char*)xs + 16384 + off);  // rows 8-15
            const __half2 a0 = *(const __half2*)&g0.x;
            const __half2 a1 = *(const __half2*)&g0.y;
            const __half2 a2 = *(const __half2*)&g0.z;
            const __half2 a3 = *(const __half2*)&g0.w;
            const __half2 b0h = *(const __half2*)&g1.x;
            const __half2 b1h = *(const __half2*)&g1.y;
            const __half2 b2h = *(const __half2*)&g1.z;
            const __half2 b3h = *(const __half2*)&g1.w;
            acc[0]  = fmaf(v, __low2float(a0),  acc[0]);
            acc[1]  = fmaf(v, __high2float(a0), acc[1]);
            acc[2]  = fmaf(v, __low2float(a1),  acc[2]);
            acc[3]  = fmaf(v, __high2float(a1), acc[3]);
            acc[4]  = fmaf(v, __low2float(a2),  acc[4]);
            acc[5]  = fmaf(v, __high2float(a2), acc[5]);
            acc[6]  = fmaf(v, __low2float(a3),  acc[6]);
            acc[7]  = fmaf(v, __high2float(a3), acc[7]);
            acc[8]  = fmaf(v, __low2float(b0h),  acc[8]);
            acc[9]  = fmaf(v, __high2float(b0h), acc[9]);
            acc[10] = fmaf(v, __low2float(b1h),  acc[10]);
            acc[11] = fmaf(v, __high2float(b1h), acc[11]);
            acc[12] = fmaf(v, __low2float(b2h),  acc[12]);
            acc[13] = fmaf(v, __high2float(b2h), acc[13]);
            acc[14] = fmaf(v, __low2float(b3h),  acc[14]);
            acc[15] = fmaf(v, __high2float(b3h), acc[15]);
        }

        // ---- store this no-group now: spreads the 168 MB write stream across
        // the kernel (overlaps with the next group's LDS gathers) and keeps
        // only 16 accs live. Coalesced per row; nontemporal so the write
        // stream does not evict L2-resident xpk / pmeta. ----
        const int o = obase + no * THREADS;
#pragma unroll
        for (int r = 0; r < BT; ++r) {
            __builtin_nontemporal_store(acc[r], &y[(size_t)(b0 + r) * OUT + o]);
        }
    }
}

extern "C" void kernel_launch(void* const* d_in, const int* in_sizes, int n_in,
                              void* d_out, int out_size, void* d_ws, size_t ws_size,
                              hipStream_t stream) {
    const float* x    = (const float*)d_in[0];   // [1024, 1024] fp32
    const float* vals = (const float*)d_in[1];   // [40960, 7]  fp32
    const int*   idx  = (const int*)d_in[2];     // [40960, 7]  int32
    float*       y    = (float*)d_out;           // [1024, 40960] fp32

    uint2*  pmeta = (uint2*)d_ws;
    __half* xpk   = (__half*)((char*)d_ws + PMETA_BYTES);

    // 512 blocks for xpk (131072 threads) + 1120 blocks for pmeta (286720)
    repack_kernel<<<dim3(512 + 1120), dim3(THREADS), 0, stream>>>(
        x, vals, idx, pmeta, xpk);

    dim3 grid(OUT / OTILE, BATCH / BT);          // (40, 64) = 2560 blocks
    sparse_proj<<<grid, dim3(THREADS), 0, stream>>>(pmeta, xpk, y);
}

// Round 6
// 174.030 us; speedup vs baseline: 1.0215x; 1.0215x over previous
//
#include <hip/hip_runtime.h>
#include <hip/hip_fp16.h>

#define BATCH   1024
#define IN      1024
#define OUT     40960
#define KF      7
#define BT      16           // batch rows per block: two 8-row fp16 tables
#define NO      4            // output columns per thread
#define THREADS 256
#define OTILE   (THREADS * NO)   // 1024 outputs per block
#define CHUNKS  (OUT / 64)       // 640 chunks of 64 consecutive outputs

// Workspace layout (repacked once per launch by repack_kernel):
//   pmeta : uint2 [CHUNKS][KF][64]  {x = idx<<4 (LDS byte off), y = f32 val bits}
//   xpk   : f16   [BATCH/8][IN][8]  x rounded fp16, 8 batch rows per 16-B granule
#define PMETA_BYTES ((size_t)CHUNKS * KF * 64 * 8)        // 2,293,760
#define XPK_BYTES   ((size_t)(BATCH / 8) * IN * 8 * 2)    // 2,097,152

// Round-4/5 theory under test: per-wave IN-ORDER vmcnt counts stores, so each
// no-group's meta-load waitcnt drained the PREVIOUS group's 16 nt stores all
// the way to HBM (~1000cy, nt = no L2 allocate) -- the invariant ~30us gap.
// Fixes: (1) plain stores (retire at L2; L3 backs the 4.4 MB of inputs),
// (2) next group's meta loads issued BEFORE this group's FMAs+stores, so
// their waitcnt does not imply store drain (loads older in vmem queue).
// Round 5 failed on a prefetch-address bug (offset *448 instead of *1792);
// fixed here: group stride in uint2 records is 4 chunks * KF*64 = 1792.

__global__ __launch_bounds__(THREADS)
void repack_kernel(const float* __restrict__ x, const float* __restrict__ vals,
                   const int* __restrict__ idx,
                   uint2* __restrict__ pmeta, __half* __restrict__ xpk)
{
    const int gid = blockIdx.x * THREADS + threadIdx.x;
    if (blockIdx.x < 512) {
        // ---- part A: x[1024][1024] f32 -> xpk[g][i][8] f16 ----
        const int g = gid >> 10;        // batch group 0..127
        const int i = gid & 1023;       // column
        const float* xb = x + (size_t)g * 8 * IN + i;
        union { __half h[8]; float4 f; } u;
#pragma unroll
        for (int r = 0; r < 8; ++r) u.h[r] = __float2half_rn(xb[(size_t)r * IN]);
        *(float4*)&xpk[(size_t)gid * 8] = u.f;   // coalesced 16-B store
    } else {
        // ---- part B: idx/vals [OUT][KF] -> pmeta[CHUNKS][KF][64] ----
        const int t2 = gid - 512 * THREADS;      // 0 .. 286719
        const int c  = t2 / (KF * 64);
        const int r  = t2 % (KF * 64);
        const int k  = r >> 6;
        const int l  = r & 63;
        const size_t src = (size_t)(c * 64 + l) * KF + k;
        uint2 m;
        m.x = (unsigned)(idx[src] << 4);         // byte offset into xs table
        m.y = __float_as_uint(vals[src]);
        pmeta[t2] = m;
    }
}

__global__ __launch_bounds__(THREADS, 5)
void sparse_proj(const uint2* __restrict__ pmeta, const __half* __restrict__ xpk,
                 float* __restrict__ y)
{
    // two 8-row tables, 16 KB apart: xs[h*8192 + i*16B] = rows b0+8h .. b0+8h+7
    __shared__ __align__(16) __half xs[2 * IN * 8];   // 32 KB -> 5 blocks/CU

    const int t     = threadIdx.x;
    const int b0    = blockIdx.y * BT;
    const int obase = blockIdx.x * OTILE + t;

    // ---- stage: straight 32 KB copy, already fp16 + gather-layout ----
    {
        const float4* src = (const float4*)(xpk + (size_t)blockIdx.y * 2 * IN * 8);
        float4* dst = (float4*)xs;
#pragma unroll
        for (int r = 0; r < 8; ++r) dst[t + r * THREADS] = src[t + r * THREADS];
    }
    __syncthreads();

    const int w    = t >> 6;
    const int lane = t & 63;

    // Group no's chunk: c = blockIdx.x*16 + no*4 + w.
    // Record offset from mbase (in uint2): no * 4 * (KF*64) + k*64.
    const uint2* mbase = pmeta + (size_t)(blockIdx.x * 16 + w) * (KF * 64) + lane;

    // double-buffered meta registers (statically indexed after unroll)
    uint2 mc[KF], mn[KF];
#pragma unroll
    for (int k = 0; k < KF; ++k) mc[k] = mbase[k * 64];   // group 0

#pragma unroll
    for (int no = 0; no < NO; ++no) {
        // ---- prefetch NEXT group's meta before this group's stores ----
        if (no + 1 < NO) {
#pragma unroll
            for (int k = 0; k < KF; ++k)
                mn[k] = mbase[(size_t)(no + 1) * 4 * (KF * 64) + k * 64];
        }

        float acc[BT];
#pragma unroll
        for (int r = 0; r < BT; ++r) acc[r] = 0.0f;

#pragma unroll
        for (int k = 0; k < KF; ++k) {
            const unsigned off = mc[k].x;            // i*16
            const float v = __uint_as_float(mc[k].y);
            const float4 g0 = *(const float4*)((const char*)xs + off);          // rows 0-7
            const float4 g1 = *(const float4*)((const char*)xs + 16384 + off);  // rows 8-15
            const __half2 a0 = *(const __half2*)&g0.x;
            const __half2 a1 = *(const __half2*)&g0.y;
            const __half2 a2 = *(const __half2*)&g0.z;
            const __half2 a3 = *(const __half2*)&g0.w;
            const __half2 c0 = *(const __half2*)&g1.x;
            const __half2 c1 = *(const __half2*)&g1.y;
            const __half2 c2 = *(const __half2*)&g1.z;
            const __half2 c3 = *(const __half2*)&g1.w;
            acc[0]  = fmaf(v, __low2float(a0),  acc[0]);
            acc[1]  = fmaf(v, __high2float(a0), acc[1]);
            acc[2]  = fmaf(v, __low2float(a1),  acc[2]);
            acc[3]  = fmaf(v, __high2float(a1), acc[3]);
            acc[4]  = fmaf(v, __low2float(a2),  acc[4]);
            acc[5]  = fmaf(v, __high2float(a2), acc[5]);
            acc[6]  = fmaf(v, __low2float(a3),  acc[6]);
            acc[7]  = fmaf(v, __high2float(a3), acc[7]);
            acc[8]  = fmaf(v, __low2float(c0),  acc[8]);
            acc[9]  = fmaf(v, __high2float(c0), acc[9]);
            acc[10] = fmaf(v, __low2float(c1),  acc[10]);
            acc[11] = fmaf(v, __high2float(c1), acc[11]);
            acc[12] = fmaf(v, __low2float(c2),  acc[12]);
            acc[13] = fmaf(v, __high2float(c2), acc[13]);
            acc[14] = fmaf(v, __low2float(c3),  acc[14]);
            acc[15] = fmaf(v, __high2float(c3), acc[15]);
        }

        // ---- store this group now (plain stores: retire at L2, no HBM
        // drain on the next group's waitcnt). Coalesced 256 B per wave. ----
        const int o = obase + no * THREADS;
#pragma unroll
        for (int r = 0; r < BT; ++r) {
            y[(size_t)(b0 + r) * OUT + o] = acc[r];
        }

        // rotate meta buffers (register moves, statically unrolled)
#pragma unroll
        for (int k = 0; k < KF; ++k) mc[k] = mn[k];
    }
}

extern "C" void kernel_launch(void* const* d_in, const int* in_sizes, int n_in,
                              void* d_out, int out_size, void* d_ws, size_t ws_size,
                              hipStream_t stream) {
    const float* x    = (const float*)d_in[0];   // [1024, 1024] fp32
    const float* vals = (const float*)d_in[1];   // [40960, 7]  fp32
    const int*   idx  = (const int*)d_in[2];     // [40960, 7]  int32
    float*       y    = (float*)d_out;           // [1024, 40960] fp32

    uint2*  pmeta = (uint2*)d_ws;
    __half* xpk   = (__half*)((char*)d_ws + PMETA_BYTES);

    // 512 blocks for xpk (131072 threads) + 1120 blocks for pmeta (286720)
    repack_kernel<<<dim3(512 + 1120), dim3(THREADS), 0, stream>>>(
        x, vals, idx, pmeta, xpk);

    dim3 grid(OUT / OTILE, BATCH / BT);          // (40, 64) = 2560 blocks
    sparse_proj<<<grid, dim3(THREADS), 0, stream>>>(pmeta, xpk, y);
}